// Round 2
// baseline (267.941 us; speedup 1.0000x reference)
//
#include <hip/hip_runtime.h>

// 2-layer GCN. memset(bcnt+deg) -> part (bucket partition + per-node degree
// atomics) -> sortgemm (4-way quarter-split per-bucket counting sort FUSED
// with the layer-1 GEMM as extra blocks; gemm computes dinv locally from deg
// so hhat is written PRE-SCALED, keeping agg1's gather path minimal) ->
// agg1 (dual-node waves, fused layer-2 GEMV) -> agg2 (dual-node waves).
// Lessons: ch-blocking (r11) and quad-node (r12) regress; dual-node is the
// MLP/occupancy equilibrium; agg1 is L2-miss-concurrency bound at
// ~11 MB/XCD / ~250 GB/s ~= 44 us (per-XCD compulsory fabric floor) — do NOT
// add anything to its load chain (per-edge dinv loads cost +12 us, r1).

namespace {
constexpr int BLK = 256;
constexpr int NPB = 256;       // nodes per bucket (dstLocal fits in 8 bits)
constexpr int PCHUNK = 8192;   // edges per partition block
constexpr int STRIDE = 5120;   // padded region per bucket: mean 4096 + 16 sigma
constexpr int CPAD = 32;       // bcnt padding: 1 counter per 128 B line

__device__ inline float bf2f(unsigned short h) {
    union { unsigned u; float f; } v; v.u = (unsigned)h << 16; return v.f;
}
__device__ inline unsigned short f2bf(float f) {
    union { float f; unsigned u; } v; v.f = f;
    unsigned r = (v.u + 0x7FFFu + ((v.u >> 16) & 1u)) >> 16;  // RNE
    return (unsigned short)r;
}
__device__ inline unsigned pack2bf(float a, float b) {
    return (unsigned)f2bf(a) | ((unsigned)f2bf(b) << 16);
}
// select one of 4 scalar edge ids by lane slot q (0..3) — cndmask tree
__device__ inline int sel4(int s0, int s1, int s2, int s3, int q) {
    int sa = (q & 1) ? s1 : s0;
    int sb = (q & 1) ? s3 : s2;
    return (q & 2) ? sb : sa;
}

// 8 / 4-edge gather helpers (indices wave-uniform -> scalar cache).
// hhat rows are PRE-SCALED by dinv[src]; keep this chain minimal (r1 lesson).
__device__ inline float gather8(const unsigned short* __restrict__ hhat,
                                const int* __restrict__ ssrc, int base, int lane) {
    int s0 = ssrc[base + 0], s1 = ssrc[base + 1];
    int s2 = ssrc[base + 2], s3 = ssrc[base + 3];
    int s4 = ssrc[base + 4], s5 = ssrc[base + 5];
    int s6 = ssrc[base + 6], s7 = ssrc[base + 7];
    float v0 = bf2f(hhat[((size_t)s0 << 6) + lane]);
    float v1 = bf2f(hhat[((size_t)s1 << 6) + lane]);
    float v2 = bf2f(hhat[((size_t)s2 << 6) + lane]);
    float v3 = bf2f(hhat[((size_t)s3 << 6) + lane]);
    float v4 = bf2f(hhat[((size_t)s4 << 6) + lane]);
    float v5 = bf2f(hhat[((size_t)s5 << 6) + lane]);
    float v6 = bf2f(hhat[((size_t)s6 << 6) + lane]);
    float v7 = bf2f(hhat[((size_t)s7 << 6) + lane]);
    return ((v0 + v1) + (v2 + v3)) + ((v4 + v5) + (v6 + v7));
}
__device__ inline float gather4(const unsigned short* __restrict__ hhat,
                                const int* __restrict__ ssrc, int base, int lane) {
    int s0 = ssrc[base + 0], s1 = ssrc[base + 1];
    int s2 = ssrc[base + 2], s3 = ssrc[base + 3];
    float v0 = bf2f(hhat[((size_t)s0 << 6) + lane]);
    float v1 = bf2f(hhat[((size_t)s1 << 6) + lane]);
    float v2 = bf2f(hhat[((size_t)s2 << 6) + lane]);
    float v3 = bf2f(hhat[((size_t)s3 << 6) + lane]);
    return (v0 + v1) + (v2 + v3);
}

// ---- stage 1: single-pass partition into fixed bucket regions --------------
// Also accumulates per-node in-degree (global atomics, 100K counters) so the
// layer-1 GEMM can compute dinv WITHOUT waiting for the sort.
__global__ __launch_bounds__(BLK) void k_part(const int* __restrict__ src,
                                              const int* __restrict__ dst,
                                              int* __restrict__ bcnt,
                                              int* __restrict__ deg,
                                              unsigned* __restrict__ packed,
                                              int e, int nb) {
    __shared__ int hist[1024];
    __shared__ int base[1024];
    int t = threadIdx.x;
    int chunk0 = blockIdx.x * PCHUNK;
    if (chunk0 >= e) return;
    int lim = min(PCHUNK, e - chunk0);
    int lim4 = lim >> 2;
    for (int i = t; i < nb; i += BLK) hist[i] = 0;
    __syncthreads();
    const int4* d4 = (const int4*)(dst + chunk0);
    for (int i = t; i < lim4; i += BLK) {
        int4 d = d4[i];
        atomicAdd(&hist[d.x >> 8], 1);
        atomicAdd(&hist[d.y >> 8], 1);
        atomicAdd(&hist[d.z >> 8], 1);
        atomicAdd(&hist[d.w >> 8], 1);
        atomicAdd(&deg[d.x], 1);
        atomicAdd(&deg[d.y], 1);
        atomicAdd(&deg[d.z], 1);
        atomicAdd(&deg[d.w], 1);
    }
    for (int i = (lim4 << 2) + t; i < lim; i += BLK) {
        int d = dst[chunk0 + i];
        atomicAdd(&hist[d >> 8], 1);
        atomicAdd(&deg[d], 1);
    }
    __syncthreads();
    for (int i = t; i < nb; i += BLK) {
        int c = hist[i];
        base[i] = c ? (i * STRIDE + atomicAdd(&bcnt[i * CPAD], c)) : 0;
        hist[i] = 0;  // reuse as within-chunk cursor
    }
    __syncthreads();
    const int4* s4 = (const int4*)(src + chunk0);
    for (int i = t; i < lim4; i += BLK) {
        int4 d = d4[i];
        int4 s = s4[i];
        int b0 = d.x >> 8, b1 = d.y >> 8, b2 = d.z >> 8, b3 = d.w >> 8;
        int r0 = atomicAdd(&hist[b0], 1);
        packed[base[b0] + r0] = ((unsigned)s.x << 8) | (unsigned)(d.x & 255);
        int r1 = atomicAdd(&hist[b1], 1);
        packed[base[b1] + r1] = ((unsigned)s.y << 8) | (unsigned)(d.y & 255);
        int r2 = atomicAdd(&hist[b2], 1);
        packed[base[b2] + r2] = ((unsigned)s.z << 8) | (unsigned)(d.z & 255);
        int r3 = atomicAdd(&hist[b3], 1);
        packed[base[b3] + r3] = ((unsigned)s.w << 8) | (unsigned)(d.w & 255);
    }
    for (int i = (lim4 << 2) + t; i < lim; i += BLK) {
        int d = dst[chunk0 + i];
        int b = d >> 8;
        int r = atomicAdd(&hist[b], 1);
        packed[base[b] + r] = ((unsigned)src[chunk0 + i] << 8) | (unsigned)(d & 255);
    }
}

// ---- stage 2: counting sort FUSED with layer-1 GEMM ------------------------
// Blocks [0, nsort): 4-way quarter-split per-bucket counting sort (unchanged
// structure). Blocks [nsort, nsort+g1): layer-1 GEMM; dinv computed locally
// from deg (ready since k_part), hhat written PRE-SCALED bf16.
// LDS is a union: sort staging (22.5 KB) vs W tile (16 KB).
union SMemU {
    struct { unsigned sp[STRIDE]; int cnt[NPB]; int offs[NPB]; } s;
    float W[64 * 64];
};

__global__ __launch_bounds__(BLK) void k_sortgemm(
    const unsigned* __restrict__ packed, const int* __restrict__ bcnt,
    int* __restrict__ ssrc, int* __restrict__ rowbeg, int* __restrict__ rowcnt,
    float* __restrict__ dinv, int n, int nsort,
    const float* __restrict__ x, const float* __restrict__ W1,
    const int* __restrict__ deg,
    unsigned short* __restrict__ hhat, int ntiles) {
    __shared__ SMemU sm;
    int t = threadIdx.x;
    if ((int)blockIdx.x < nsort) {
        // ---------------- sort role ----------------
        int bid = blockIdx.x;
        int b = bid >> 2;
        int qr = bid & 3;                  // quarter: local nodes qr*64 .. +63
        int regionBase = b * STRIDE;
        int ecnt = bcnt[b * CPAD];
        sm.s.cnt[t] = 0;
        __syncthreads();
        for (int i = t; i < ecnt; i += BLK) {
            unsigned p = packed[regionBase + i];
            sm.s.sp[i] = p;
            atomicAdd(&sm.s.cnt[p & 255u], 1);
        }
        __syncthreads();
        int v = sm.s.cnt[t];
        sm.s.offs[t] = v;
        __syncthreads();
        for (int off = 1; off < NPB; off <<= 1) {
            int xx = (t >= off) ? sm.s.offs[t - off] : 0;
            __syncthreads();
            sm.s.offs[t] += xx;
            __syncthreads();
        }
        int myoff = sm.s.offs[t] - v;  // exclusive
        int node = (b << 8) + t;
        if ((t >> 6) == qr && node < n) {
            rowbeg[node] = regionBase + myoff;
            rowcnt[node] = v;
            dinv[node] = rsqrtf((float)(v + 1));   // +1 self-loop
        }
        __syncthreads();
        sm.s.cnt[t] = regionBase + myoff;  // reuse as cursor
        __syncthreads();
        int lo = qr << 6, hi = lo + 64;
        for (int i = t; i < ecnt; i += BLK) {
            unsigned p = sm.s.sp[i];
            int dl = (int)(p & 255u);
            if (dl >= lo && dl < hi) {
                int pos = atomicAdd(&sm.s.cnt[dl], 1);
                ssrc[pos] = (int)(p >> 8);
            }
        }
    } else {
        // ---------------- gemm role ----------------
        // hhat[n][c] = bf16( dinv[n] * sum_k x[n][k]*W1[k][c] ), dinv from deg
        #pragma unroll
        for (int i = 0; i < 16; ++i) sm.W[t + BLK * i] = W1[t + BLK * i];
        __syncthreads();
        const int cg = t & 3;
        const int ng = t >> 2;
        const float* Wc = sm.W + cg * 16;
        const int g1grid = gridDim.x - nsort;

        for (int tile = blockIdx.x - nsort; tile < ntiles; tile += g1grid) {
            const int node0 = tile * 256 + ng * 4;
            int nd[4];
            #pragma unroll
            for (int i = 0; i < 4; ++i) {
                int vv = node0 + i;
                nd[i] = (vv < n) ? vv : (n - 1);
            }
            float4 acc[4][4];
            #pragma unroll
            for (int i = 0; i < 4; ++i)
                #pragma unroll
                for (int c = 0; c < 4; ++c) acc[i][c] = make_float4(0.f, 0.f, 0.f, 0.f);

            for (int k4 = 0; k4 < 16; ++k4) {
                float4 xv[4];
                #pragma unroll
                for (int i = 0; i < 4; ++i)
                    xv[i] = ((const float4*)(x + (size_t)nd[i] * 64))[k4];
                #pragma unroll
                for (int kk = 0; kk < 4; ++kk) {
                    const float4* wr = (const float4*)(Wc + (k4 * 4 + kk) * 64);
                    float4 w0 = wr[0], w1 = wr[1], w2 = wr[2], w3 = wr[3];
                    #pragma unroll
                    for (int i = 0; i < 4; ++i) {
                        float xa[4] = {xv[i].x, xv[i].y, xv[i].z, xv[i].w};
                        float xs = xa[kk];
                        acc[i][0].x = fmaf(xs, w0.x, acc[i][0].x);
                        acc[i][0].y = fmaf(xs, w0.y, acc[i][0].y);
                        acc[i][0].z = fmaf(xs, w0.z, acc[i][0].z);
                        acc[i][0].w = fmaf(xs, w0.w, acc[i][0].w);
                        acc[i][1].x = fmaf(xs, w1.x, acc[i][1].x);
                        acc[i][1].y = fmaf(xs, w1.y, acc[i][1].y);
                        acc[i][1].z = fmaf(xs, w1.z, acc[i][1].z);
                        acc[i][1].w = fmaf(xs, w1.w, acc[i][1].w);
                        acc[i][2].x = fmaf(xs, w2.x, acc[i][2].x);
                        acc[i][2].y = fmaf(xs, w2.y, acc[i][2].y);
                        acc[i][2].z = fmaf(xs, w2.z, acc[i][2].z);
                        acc[i][2].w = fmaf(xs, w2.w, acc[i][2].w);
                        acc[i][3].x = fmaf(xs, w3.x, acc[i][3].x);
                        acc[i][3].y = fmaf(xs, w3.y, acc[i][3].y);
                        acc[i][3].z = fmaf(xs, w3.z, acc[i][3].z);
                        acc[i][3].w = fmaf(xs, w3.w, acc[i][3].w);
                    }
                }
            }
            #pragma unroll
            for (int i = 0; i < 4; ++i) {
                int vv = node0 + i;
                if (vv < n) {
                    float d = rsqrtf((float)(deg[vv] + 1));  // == sort's dinv[vv]
                    unsigned u0 = pack2bf(acc[i][0].x * d, acc[i][0].y * d);
                    unsigned u1 = pack2bf(acc[i][0].z * d, acc[i][0].w * d);
                    unsigned u2 = pack2bf(acc[i][1].x * d, acc[i][1].y * d);
                    unsigned u3 = pack2bf(acc[i][1].z * d, acc[i][1].w * d);
                    unsigned u4 = pack2bf(acc[i][2].x * d, acc[i][2].y * d);
                    unsigned u5 = pack2bf(acc[i][2].z * d, acc[i][2].w * d);
                    unsigned u6 = pack2bf(acc[i][3].x * d, acc[i][3].y * d);
                    unsigned u7 = pack2bf(acc[i][3].z * d, acc[i][3].w * d);
                    uint4* dstp = (uint4*)(hhat + (size_t)vv * 64 + cg * 16);
                    dstp[0] = make_uint4(u0, u1, u2, u3);
                    dstp[1] = make_uint4(u4, u5, u6, u7);
                }
            }
        }
    }
}

// ---- layer kernels ---------------------------------------------------------

// DUAL-node wave: nodes 2w and 2w+1, lane = channel (64). Interleaved 8-edge
// batches (up to 16 gathers in flight). All metadata/index loads wave-uniform.
// hhat PRE-SCALED by dinv[src]. Fused layer-2 GEMV epilogue per node.
__global__ __launch_bounds__(BLK) void k_agg1(const unsigned short* __restrict__ hhat,
                                              const int* __restrict__ rowbeg,
                                              const int* __restrict__ rowcnt,
                                              const int* __restrict__ ssrc,
                                              const float* __restrict__ dinv,
                                              const float* __restrict__ b1,
                                              const float* __restrict__ W2,
                                              unsigned short* __restrict__ h2hat, int n) {
    int pair = __builtin_amdgcn_readfirstlane(
        (int)((blockIdx.x * BLK + threadIdx.x) >> 6));
    int lane = threadIdx.x & 63;
    int wid0 = pair << 1;
    if (wid0 >= n) return;
    int wid1 = wid0 + 1;
    bool has1 = (wid1 < n);
    const int g = lane >> 4;   // c-group for the fused GEMV
    const int j = lane & 15;   // output channel for the fused GEMV
    float w2r[16];
    #pragma unroll
    for (int k = 0; k < 16; ++k) w2r[k] = W2[(g * 16 + k) * 16 + j];

    int beg0 = rowbeg[wid0], cnt0 = rowcnt[wid0];
    int beg1 = 0, cnt1 = 0;
    if (has1) { beg1 = rowbeg[wid1]; cnt1 = rowcnt[wid1]; }
    float a0 = bf2f(hhat[((size_t)wid0 << 6) + lane]);  // self-loop
    float a1 = 0.f;
    if (has1) a1 = bf2f(hhat[((size_t)wid1 << 6) + lane]);
    int e0 = 0, e1 = 0;
    // interleaved main: 16 gathers in flight
    while (e0 + 8 <= cnt0 && e1 + 8 <= cnt1) {
        float r0 = gather8(hhat, ssrc, beg0 + e0, lane);
        float r1 = gather8(hhat, ssrc, beg1 + e1, lane);
        a0 += r0;
        a1 += r1;
        e0 += 8; e1 += 8;
    }
    for (; e0 + 8 <= cnt0; e0 += 8) a0 += gather8(hhat, ssrc, beg0 + e0, lane);
    for (; e1 + 8 <= cnt1; e1 += 8) a1 += gather8(hhat, ssrc, beg1 + e1, lane);
    if (e0 + 4 <= cnt0) { a0 += gather4(hhat, ssrc, beg0 + e0, lane); e0 += 4; }
    if (e1 + 4 <= cnt1) { a1 += gather4(hhat, ssrc, beg1 + e1, lane); e1 += 4; }
    for (; e0 < cnt0; ++e0) a0 += bf2f(hhat[((size_t)ssrc[beg0 + e0] << 6) + lane]);
    for (; e1 < cnt1; ++e1) a1 += bf2f(hhat[((size_t)ssrc[beg1 + e1] << 6) + lane]);

    // fused GEMV epilogue, node 0
    {
        float dv = dinv[wid0];
        float h = fmaxf(fmaf(dv, a0, b1[lane]), 0.f);
        float part = 0.f;
        #pragma unroll
        for (int k = 0; k < 16; ++k)
            part = fmaf(__shfl(h, g * 16 + k, 64), w2r[k], part);
        part += __shfl_xor(part, 16, 64);
        part += __shfl_xor(part, 32, 64);
        if (g == 0) h2hat[(size_t)wid0 * 16 + j] = f2bf(part * dv);
    }
    if (has1) {
        float dv = dinv[wid1];
        float h = fmaxf(fmaf(dv, a1, b1[lane]), 0.f);
        float part = 0.f;
        #pragma unroll
        for (int k = 0; k < 16; ++k)
            part = fmaf(__shfl(h, g * 16 + k, 64), w2r[k], part);
        part += __shfl_xor(part, 16, 64);
        part += __shfl_xor(part, 32, 64);
        if (g == 0) h2hat[(size_t)wid1 * 16 + j] = f2bf(part * dv);
    }
}

// DUAL-node wave layer 2: nodes 2w, 2w+1; 64 lanes = 4 edge-slots x 16 ch;
// uniform ssrc loads + cndmask select by slot; interleaved 8-edge batches.
__global__ __launch_bounds__(BLK) void k_agg2(const unsigned short* __restrict__ h2,
                                              const int* __restrict__ rowbeg,
                                              const int* __restrict__ rowcnt,
                                              const int* __restrict__ ssrc,
                                              const float* __restrict__ dinv,
                                              const float* __restrict__ b2,
                                              float* __restrict__ out, int n) {
    int pair = __builtin_amdgcn_readfirstlane(
        (int)((blockIdx.x * BLK + threadIdx.x) >> 6));
    int lane = threadIdx.x & 63;
    int w0 = pair << 1;
    if (w0 >= n) return;
    int w1 = w0 + 1;
    bool has1 = (w1 < n);
    int q = lane >> 4;      // edge slot 0..3
    int c = lane & 15;      // channel
    int beg0 = rowbeg[w0], cnt0 = rowcnt[w0];
    int beg1 = 0, cnt1 = 0;
    if (has1) { beg1 = rowbeg[w1]; cnt1 = rowcnt[w1]; }
    float a0 = 0.f, a1 = 0.f;
    int e0 = 0, e1 = 0;
    while (e0 + 8 <= cnt0 && e1 + 8 <= cnt1) {
        int p0 = beg0 + e0, p1 = beg1 + e1;
        int x0 = ssrc[p0 + 0], x1 = ssrc[p0 + 1], x2 = ssrc[p0 + 2], x3 = ssrc[p0 + 3];
        int x4 = ssrc[p0 + 4], x5 = ssrc[p0 + 5], x6 = ssrc[p0 + 6], x7 = ssrc[p0 + 7];
        int y0 = ssrc[p1 + 0], y1 = ssrc[p1 + 1], y2 = ssrc[p1 + 2], y3 = ssrc[p1 + 3];
        int y4 = ssrc[p1 + 4], y5 = ssrc[p1 + 5], y6 = ssrc[p1 + 6], y7 = ssrc[p1 + 7];
        int sA0 = sel4(x0, x1, x2, x3, q), sB0 = sel4(x4, x5, x6, x7, q);
        int sA1 = sel4(y0, y1, y2, y3, q), sB1 = sel4(y4, y5, y6, y7, q);
        float vA0 = bf2f(h2[((size_t)sA0 << 4) + c]);
        float vB0 = bf2f(h2[((size_t)sB0 << 4) + c]);
        float vA1 = bf2f(h2[((size_t)sA1 << 4) + c]);
        float vB1 = bf2f(h2[((size_t)sB1 << 4) + c]);
        a0 += vA0 + vB0;
        a1 += vA1 + vB1;
        e0 += 8; e1 += 8;
    }
    // drain node 0
    for (; e0 + 8 <= cnt0; e0 += 8) {
        int p0 = beg0 + e0;
        int x0 = ssrc[p0 + 0], x1 = ssrc[p0 + 1], x2 = ssrc[p0 + 2], x3 = ssrc[p0 + 3];
        int x4 = ssrc[p0 + 4], x5 = ssrc[p0 + 5], x6 = ssrc[p0 + 6], x7 = ssrc[p0 + 7];
        int sA = sel4(x0, x1, x2, x3, q), sB = sel4(x4, x5, x6, x7, q);
        a0 += bf2f(h2[((size_t)sA << 4) + c]) + bf2f(h2[((size_t)sB << 4) + c]);
    }
    if (e0 + 4 <= cnt0) {
        int p0 = beg0 + e0;
        int x0 = ssrc[p0 + 0], x1 = ssrc[p0 + 1], x2 = ssrc[p0 + 2], x3 = ssrc[p0 + 3];
        a0 += bf2f(h2[((size_t)sel4(x0, x1, x2, x3, q) << 4) + c]);
        e0 += 4;
    }
    if (e0 + q < cnt0)
        a0 += bf2f(h2[((size_t)ssrc[beg0 + e0 + q] << 4) + c]);
    // drain node 1
    for (; e1 + 8 <= cnt1; e1 += 8) {
        int p1 = beg1 + e1;
        int y0 = ssrc[p1 + 0], y1 = ssrc[p1 + 1], y2 = ssrc[p1 + 2], y3 = ssrc[p1 + 3];
        int y4 = ssrc[p1 + 4], y5 = ssrc[p1 + 5], y6 = ssrc[p1 + 6], y7 = ssrc[p1 + 7];
        int sA = sel4(y0, y1, y2, y3, q), sB = sel4(y4, y5, y6, y7, q);
        a1 += bf2f(h2[((size_t)sA << 4) + c]) + bf2f(h2[((size_t)sB << 4) + c]);
    }
    if (has1 && e1 + 4 <= cnt1) {
        int p1 = beg1 + e1;
        int y0 = ssrc[p1 + 0], y1 = ssrc[p1 + 1], y2 = ssrc[p1 + 2], y3 = ssrc[p1 + 3];
        a1 += bf2f(h2[((size_t)sel4(y0, y1, y2, y3, q) << 4) + c]);
        e1 += 4;
    }
    if (has1 && e1 + q < cnt1)
        a1 += bf2f(h2[((size_t)ssrc[beg1 + e1 + q] << 4) + c]);

    a0 += __shfl_xor(a0, 16, 64);
    a0 += __shfl_xor(a0, 32, 64);
    a1 += __shfl_xor(a1, 16, 64);
    a1 += __shfl_xor(a1, 32, 64);
    if (q == 0) {
        float self0 = bf2f(h2[((size_t)w0 << 4) + c]);
        out[((size_t)w0 << 4) + c] = fmaf(dinv[w0], a0 + self0, b2[c]);
        if (has1) {
            float self1 = bf2f(h2[((size_t)w1 << 4) + c]);
            out[((size_t)w1 << 4) + c] = fmaf(dinv[w1], a1 + self1, b2[c]);
        }
    }
}

} // namespace

extern "C" void kernel_launch(void* const* d_in, const int* in_sizes, int n_in,
                              void* d_out, int out_size, void* d_ws, size_t ws_size,
                              hipStream_t stream) {
    const float* x  = (const float*)d_in[0];
    const int*   ei = (const int*)d_in[1];
    const float* W1 = (const float*)d_in[2];
    const float* b1 = (const float*)d_in[3];
    const float* W2 = (const float*)d_in[4];
    const float* b2 = (const float*)d_in[5];
    float* out = (float*)d_out;

    const int N = in_sizes[0] / 64;
    const int E = in_sizes[1] / 2;
    const int* src = ei;
    const int* dst = ei + E;
    const int nb = (N + NPB - 1) / NPB;   // buckets (<=1024)

    char* ws = (char*)d_ws;
    size_t off = 0;
    auto alloc = [&](size_t bytes) -> char* {
        char* p = ws + off;
        off = (off + bytes + 255) & ~(size_t)255;
        return p;
    };
    int*            bcnt   = (int*)alloc((size_t)1024 * CPAD * 4);  // 128 KB
    int*            deg    = (int*)alloc((size_t)N * 4);            // contiguous after bcnt
    int*            rowbeg = (int*)alloc((size_t)N * 4);
    int*            rowcnt = (int*)alloc((size_t)N * 4);
    float*          dinv   = (float*)alloc((size_t)N * 4);
    unsigned*       packed = (unsigned*)alloc((size_t)nb * STRIDE * 4);
    int*            ssrc   = (int*)alloc((size_t)nb * STRIDE * 4);
    unsigned short* hhat   = (unsigned short*)alloc((size_t)N * 64 * 2);
    unsigned short* h2hat  = (unsigned short*)alloc((size_t)N * 16 * 2);

    const int ntiles = (N + 255) / 256;
    const int g1grid = (ntiles < 1024) ? ntiles : 1024;
    const int nchunks = (E + PCHUNK - 1) / PCHUNK;
    const int npairs = (N + 1) / 2;
    const int nb_p = (int)(((long long)npairs * 64 + BLK - 1) / BLK);  // dual-node
    const int nsort = nb * 4;

    // zero bcnt (full padded region) + deg in one contiguous memset
    hipMemsetAsync(bcnt, 0, (size_t)1024 * CPAD * 4 + ((size_t)N * 4 + 255 & ~(size_t)255), stream);
    k_part<<<nchunks, BLK, 0, stream>>>(src, dst, bcnt, deg, packed, E, nb);
    k_sortgemm<<<nsort + g1grid, BLK, 0, stream>>>(packed, bcnt, ssrc, rowbeg,
                                                   rowcnt, dinv, N, nsort,
                                                   x, W1, deg, hhat, ntiles);
    k_agg1<<<nb_p, BLK, 0, stream>>>(hhat, rowbeg, rowcnt, ssrc, dinv, b1, W2,
                                     h2hat, N);
    k_agg2<<<nb_p, BLK, 0, stream>>>(h2hat, rowbeg, rowcnt, ssrc, dinv, b2, out, N);
}

// Round 3
// 214.287 us; speedup vs baseline: 1.2504x; 1.2504x over previous
//
#include <hip/hip_runtime.h>

// 2-layer GCN. memset(bcnt) -> part (bucket partition, padded counters,
// PCHUNK=2048 for occupancy) -> sort (4-way quarter-split per-bucket counting
// sort, 1564 blocks) -> gemm1 (grid-stride persistent, reads sort's dinv,
// writes PRE-SCALED bf16 hhat) -> agg1 (dual-node waves, fused layer-2 GEMV)
// -> agg2 (dual-node waves).
// Lessons: ch-blocking and quad-node regress; dual-node is the MLP/occupancy
// equilibrium; agg1 is L2-miss-concurrency bound (~11MB unique/XCD at
// ~250 GB/s/XCD ~= 44 us) — do NOT add anything to its gather chain (per-edge
// dinv: +12us, r1). Do NOT break the sort->gemm1 dinv dependency with global
// deg atomics: cross-XCD line ping-pong cost part +45us (r2). r2 also showed
// part is GRID-STARVED at PCHUNK=8192 (196 blocks, 7.8% occupancy ceiling):
// this round quadruples partition blocks (PCHUNK=2048).

namespace {
constexpr int BLK = 256;
constexpr int NPB = 256;       // nodes per bucket (dstLocal fits in 8 bits)
constexpr int PCHUNK = 2048;   // edges per partition block (was 8192: 7.8% occ)
constexpr int STRIDE = 5120;   // padded region per bucket: mean 4096 + 16 sigma
constexpr int CPAD = 32;       // bcnt padding: 1 counter per 128 B line

__device__ inline float bf2f(unsigned short h) {
    union { unsigned u; float f; } v; v.u = (unsigned)h << 16; return v.f;
}
__device__ inline unsigned short f2bf(float f) {
    union { float f; unsigned u; } v; v.f = f;
    unsigned r = (v.u + 0x7FFFu + ((v.u >> 16) & 1u)) >> 16;  // RNE
    return (unsigned short)r;
}
__device__ inline unsigned pack2bf(float a, float b) {
    return (unsigned)f2bf(a) | ((unsigned)f2bf(b) << 16);
}
// select one of 4 scalar edge ids by lane slot q (0..3) — cndmask tree
__device__ inline int sel4(int s0, int s1, int s2, int s3, int q) {
    int sa = (q & 1) ? s1 : s0;
    int sb = (q & 1) ? s3 : s2;
    return (q & 2) ? sb : sa;
}

// 8 / 4-edge gather helpers (indices wave-uniform -> scalar cache).
// hhat rows are PRE-SCALED by dinv[src]; keep this chain minimal (r1 lesson).
__device__ inline float gather8(const unsigned short* __restrict__ hhat,
                                const int* __restrict__ ssrc, int base, int lane) {
    int s0 = ssrc[base + 0], s1 = ssrc[base + 1];
    int s2 = ssrc[base + 2], s3 = ssrc[base + 3];
    int s4 = ssrc[base + 4], s5 = ssrc[base + 5];
    int s6 = ssrc[base + 6], s7 = ssrc[base + 7];
    float v0 = bf2f(hhat[((size_t)s0 << 6) + lane]);
    float v1 = bf2f(hhat[((size_t)s1 << 6) + lane]);
    float v2 = bf2f(hhat[((size_t)s2 << 6) + lane]);
    float v3 = bf2f(hhat[((size_t)s3 << 6) + lane]);
    float v4 = bf2f(hhat[((size_t)s4 << 6) + lane]);
    float v5 = bf2f(hhat[((size_t)s5 << 6) + lane]);
    float v6 = bf2f(hhat[((size_t)s6 << 6) + lane]);
    float v7 = bf2f(hhat[((size_t)s7 << 6) + lane]);
    return ((v0 + v1) + (v2 + v3)) + ((v4 + v5) + (v6 + v7));
}
__device__ inline float gather4(const unsigned short* __restrict__ hhat,
                                const int* __restrict__ ssrc, int base, int lane) {
    int s0 = ssrc[base + 0], s1 = ssrc[base + 1];
    int s2 = ssrc[base + 2], s3 = ssrc[base + 3];
    float v0 = bf2f(hhat[((size_t)s0 << 6) + lane]);
    float v1 = bf2f(hhat[((size_t)s1 << 6) + lane]);
    float v2 = bf2f(hhat[((size_t)s2 << 6) + lane]);
    float v3 = bf2f(hhat[((size_t)s3 << 6) + lane]);
    return (v0 + v1) + (v2 + v3);
}

// ---- stage 1: single-pass partition into fixed bucket regions --------------
__global__ __launch_bounds__(BLK) void k_part(const int* __restrict__ src,
                                              const int* __restrict__ dst,
                                              int* __restrict__ bcnt,
                                              unsigned* __restrict__ packed,
                                              int e, int nb) {
    __shared__ int hist[1024];
    __shared__ int base[1024];
    int t = threadIdx.x;
    int chunk0 = blockIdx.x * PCHUNK;
    if (chunk0 >= e) return;
    int lim = min(PCHUNK, e - chunk0);
    int lim4 = lim >> 2;
    for (int i = t; i < nb; i += BLK) hist[i] = 0;
    __syncthreads();
    const int4* d4 = (const int4*)(dst + chunk0);
    for (int i = t; i < lim4; i += BLK) {
        int4 d = d4[i];
        atomicAdd(&hist[d.x >> 8], 1);
        atomicAdd(&hist[d.y >> 8], 1);
        atomicAdd(&hist[d.z >> 8], 1);
        atomicAdd(&hist[d.w >> 8], 1);
    }
    for (int i = (lim4 << 2) + t; i < lim; i += BLK)
        atomicAdd(&hist[dst[chunk0 + i] >> 8], 1);
    __syncthreads();
    for (int i = t; i < nb; i += BLK) {
        int c = hist[i];
        base[i] = c ? (i * STRIDE + atomicAdd(&bcnt[i * CPAD], c)) : 0;
        hist[i] = 0;  // reuse as within-chunk cursor
    }
    __syncthreads();
    const int4* s4 = (const int4*)(src + chunk0);
    for (int i = t; i < lim4; i += BLK) {
        int4 d = d4[i];
        int4 s = s4[i];
        int b0 = d.x >> 8, b1 = d.y >> 8, b2 = d.z >> 8, b3 = d.w >> 8;
        int r0 = atomicAdd(&hist[b0], 1);
        packed[base[b0] + r0] = ((unsigned)s.x << 8) | (unsigned)(d.x & 255);
        int r1 = atomicAdd(&hist[b1], 1);
        packed[base[b1] + r1] = ((unsigned)s.y << 8) | (unsigned)(d.y & 255);
        int r2 = atomicAdd(&hist[b2], 1);
        packed[base[b2] + r2] = ((unsigned)s.z << 8) | (unsigned)(d.z & 255);
        int r3 = atomicAdd(&hist[b3], 1);
        packed[base[b3] + r3] = ((unsigned)s.w << 8) | (unsigned)(d.w & 255);
    }
    for (int i = (lim4 << 2) + t; i < lim; i += BLK) {
        int d = dst[chunk0 + i];
        int b = d >> 8;
        int r = atomicAdd(&hist[b], 1);
        packed[base[b] + r] = ((unsigned)src[chunk0 + i] << 8) | (unsigned)(d & 255);
    }
}

// ---- stage 2: 4-way quarter-split per-bucket counting sort -----------------
// block = (bucket b, quarter qr). All 4 blocks of a bucket redundantly build
// the 256-counter histogram + scan (cheap LDS work); each scatters only the
// edges whose dstLocal is in its 64-node quarter (contiguous sub-window).
__global__ __launch_bounds__(BLK) void k_sort(const unsigned* __restrict__ packed,
                                              const int* __restrict__ bcnt,
                                              int* __restrict__ ssrc,
                                              int* __restrict__ rowbeg,
                                              int* __restrict__ rowcnt,
                                              float* __restrict__ dinv, int n) {
    __shared__ unsigned sp[STRIDE];   // 20 KB bucket staging
    __shared__ int cnt[NPB];
    __shared__ int offs[NPB];
    int bid = blockIdx.x;
    int b = bid >> 2;
    int qr = bid & 3;                  // quarter: local nodes qr*64 .. qr*64+63
    int t = threadIdx.x;
    int regionBase = b * STRIDE;
    int ecnt = bcnt[b * CPAD];
    cnt[t] = 0;
    __syncthreads();
    for (int i = t; i < ecnt; i += BLK) {
        unsigned p = packed[regionBase + i];
        sp[i] = p;
        atomicAdd(&cnt[p & 255u], 1);
    }
    __syncthreads();
    int v = cnt[t];
    offs[t] = v;
    __syncthreads();
    for (int off = 1; off < NPB; off <<= 1) {
        int x = (t >= off) ? offs[t - off] : 0;
        __syncthreads();
        offs[t] += x;
        __syncthreads();
    }
    int myoff = offs[t] - v;  // exclusive
    int node = (b << 8) + t;
    if ((t >> 6) == qr && node < n) {
        rowbeg[node] = regionBase + myoff;
        rowcnt[node] = v;
        dinv[node] = rsqrtf((float)(v + 1));   // +1 self-loop
    }
    __syncthreads();
    cnt[t] = regionBase + myoff;  // reuse as cursor
    __syncthreads();
    int lo = qr << 6, hi = lo + 64;
    for (int i = t; i < ecnt; i += BLK) {
        unsigned p = sp[i];
        int dl = (int)(p & 255u);
        if (dl >= lo && dl < hi) {
            int pos = atomicAdd(&cnt[dl], 1);
            ssrc[pos] = (int)(p >> 8);
        }
    }
}

// ---- layer kernels ---------------------------------------------------------

// hhat[n][c] = bf16( dinv[n] * sum_k x[n][k]*W1[k][c] )
// thread = 4 nodes x 16 channels; GRID-STRIDE persistent blocks: W loaded to
// LDS once per block, then loop over 256-node tiles.
__global__ __launch_bounds__(BLK) void k_gemm1(const float* __restrict__ x,
                                               const float* __restrict__ W1,
                                               const float* __restrict__ dinv,
                                               unsigned short* __restrict__ hhat,
                                               int n, int ntiles) {
    __shared__ float W[64 * 64];
    int t = threadIdx.x;
    #pragma unroll
    for (int i = 0; i < 16; ++i) W[t + BLK * i] = W1[t + BLK * i];
    __syncthreads();
    const int cg = t & 3;
    const int ng = t >> 2;
    const float* Wc = W + cg * 16;

    for (int tile = blockIdx.x; tile < ntiles; tile += gridDim.x) {
        const int node0 = tile * 256 + ng * 4;
        int nd[4];
        #pragma unroll
        for (int i = 0; i < 4; ++i) {
            int v = node0 + i;
            nd[i] = (v < n) ? v : (n - 1);
        }
        float4 acc[4][4];
        #pragma unroll
        for (int i = 0; i < 4; ++i)
            #pragma unroll
            for (int c = 0; c < 4; ++c) acc[i][c] = make_float4(0.f, 0.f, 0.f, 0.f);

        for (int k4 = 0; k4 < 16; ++k4) {
            float4 xv[4];
            #pragma unroll
            for (int i = 0; i < 4; ++i)
                xv[i] = ((const float4*)(x + (size_t)nd[i] * 64))[k4];
            #pragma unroll
            for (int kk = 0; kk < 4; ++kk) {
                const float4* wr = (const float4*)(Wc + (k4 * 4 + kk) * 64);
                float4 w0 = wr[0], w1 = wr[1], w2 = wr[2], w3 = wr[3];
                #pragma unroll
                for (int i = 0; i < 4; ++i) {
                    float xa[4] = {xv[i].x, xv[i].y, xv[i].z, xv[i].w};
                    float xs = xa[kk];
                    acc[i][0].x = fmaf(xs, w0.x, acc[i][0].x);
                    acc[i][0].y = fmaf(xs, w0.y, acc[i][0].y);
                    acc[i][0].z = fmaf(xs, w0.z, acc[i][0].z);
                    acc[i][0].w = fmaf(xs, w0.w, acc[i][0].w);
                    acc[i][1].x = fmaf(xs, w1.x, acc[i][1].x);
                    acc[i][1].y = fmaf(xs, w1.y, acc[i][1].y);
                    acc[i][1].z = fmaf(xs, w1.z, acc[i][1].z);
                    acc[i][1].w = fmaf(xs, w1.w, acc[i][1].w);
                    acc[i][2].x = fmaf(xs, w2.x, acc[i][2].x);
                    acc[i][2].y = fmaf(xs, w2.y, acc[i][2].y);
                    acc[i][2].z = fmaf(xs, w2.z, acc[i][2].z);
                    acc[i][2].w = fmaf(xs, w2.w, acc[i][2].w);
                    acc[i][3].x = fmaf(xs, w3.x, acc[i][3].x);
                    acc[i][3].y = fmaf(xs, w3.y, acc[i][3].y);
                    acc[i][3].z = fmaf(xs, w3.z, acc[i][3].z);
                    acc[i][3].w = fmaf(xs, w3.w, acc[i][3].w);
                }
            }
        }
        #pragma unroll
        for (int i = 0; i < 4; ++i) {
            int v = node0 + i;
            if (v < n) {
                float d = dinv[v];
                unsigned u0 = pack2bf(acc[i][0].x * d, acc[i][0].y * d);
                unsigned u1 = pack2bf(acc[i][0].z * d, acc[i][0].w * d);
                unsigned u2 = pack2bf(acc[i][1].x * d, acc[i][1].y * d);
                unsigned u3 = pack2bf(acc[i][1].z * d, acc[i][1].w * d);
                unsigned u4 = pack2bf(acc[i][2].x * d, acc[i][2].y * d);
                unsigned u5 = pack2bf(acc[i][2].z * d, acc[i][2].w * d);
                unsigned u6 = pack2bf(acc[i][3].x * d, acc[i][3].y * d);
                unsigned u7 = pack2bf(acc[i][3].z * d, acc[i][3].w * d);
                uint4* dst = (uint4*)(hhat + (size_t)v * 64 + cg * 16);
                dst[0] = make_uint4(u0, u1, u2, u3);
                dst[1] = make_uint4(u4, u5, u6, u7);
            }
        }
    }
}

// DUAL-node wave: nodes 2w and 2w+1, lane = channel (64). Interleaved 8-edge
// batches (up to 16 gathers in flight). All metadata/index loads wave-uniform.
// Fused layer-2 GEMV epilogue per node. (round-10/13 verified champion)
__global__ __launch_bounds__(BLK) void k_agg1(const unsigned short* __restrict__ hhat,
                                              const int* __restrict__ rowbeg,
                                              const int* __restrict__ rowcnt,
                                              const int* __restrict__ ssrc,
                                              const float* __restrict__ dinv,
                                              const float* __restrict__ b1,
                                              const float* __restrict__ W2,
                                              unsigned short* __restrict__ h2hat, int n) {
    int pair = __builtin_amdgcn_readfirstlane(
        (int)((blockIdx.x * BLK + threadIdx.x) >> 6));
    int lane = threadIdx.x & 63;
    int wid0 = pair << 1;
    if (wid0 >= n) return;
    int wid1 = wid0 + 1;
    bool has1 = (wid1 < n);
    const int g = lane >> 4;   // c-group for the fused GEMV
    const int j = lane & 15;   // output channel for the fused GEMV
    float w2r[16];
    #pragma unroll
    for (int k = 0; k < 16; ++k) w2r[k] = W2[(g * 16 + k) * 16 + j];

    int beg0 = rowbeg[wid0], cnt0 = rowcnt[wid0];
    int beg1 = 0, cnt1 = 0;
    if (has1) { beg1 = rowbeg[wid1]; cnt1 = rowcnt[wid1]; }
    float a0 = bf2f(hhat[((size_t)wid0 << 6) + lane]);  // self-loop
    float a1 = 0.f;
    if (has1) a1 = bf2f(hhat[((size_t)wid1 << 6) + lane]);
    int e0 = 0, e1 = 0;
    // interleaved main: 16 gathers in flight
    while (e0 + 8 <= cnt0 && e1 + 8 <= cnt1) {
        float r0 = gather8(hhat, ssrc, beg0 + e0, lane);
        float r1 = gather8(hhat, ssrc, beg1 + e1, lane);
        a0 += r0;
        a1 += r1;
        e0 += 8; e1 += 8;
    }
    for (; e0 + 8 <= cnt0; e0 += 8) a0 += gather8(hhat, ssrc, beg0 + e0, lane);
    for (; e1 + 8 <= cnt1; e1 += 8) a1 += gather8(hhat, ssrc, beg1 + e1, lane);
    if (e0 + 4 <= cnt0) { a0 += gather4(hhat, ssrc, beg0 + e0, lane); e0 += 4; }
    if (e1 + 4 <= cnt1) { a1 += gather4(hhat, ssrc, beg1 + e1, lane); e1 += 4; }
    for (; e0 < cnt0; ++e0) a0 += bf2f(hhat[((size_t)ssrc[beg0 + e0] << 6) + lane]);
    for (; e1 < cnt1; ++e1) a1 += bf2f(hhat[((size_t)ssrc[beg1 + e1] << 6) + lane]);

    // fused GEMV epilogue, node 0
    {
        float dv = dinv[wid0];
        float h = fmaxf(fmaf(dv, a0, b1[lane]), 0.f);
        float part = 0.f;
        #pragma unroll
        for (int k = 0; k < 16; ++k)
            part = fmaf(__shfl(h, g * 16 + k, 64), w2r[k], part);
        part += __shfl_xor(part, 16, 64);
        part += __shfl_xor(part, 32, 64);
        if (g == 0) h2hat[(size_t)wid0 * 16 + j] = f2bf(part * dv);
    }
    if (has1) {
        float dv = dinv[wid1];
        float h = fmaxf(fmaf(dv, a1, b1[lane]), 0.f);
        float part = 0.f;
        #pragma unroll
        for (int k = 0; k < 16; ++k)
            part = fmaf(__shfl(h, g * 16 + k, 64), w2r[k], part);
        part += __shfl_xor(part, 16, 64);
        part += __shfl_xor(part, 32, 64);
        if (g == 0) h2hat[(size_t)wid1 * 16 + j] = f2bf(part * dv);
    }
}

// DUAL-node wave layer 2: nodes 2w, 2w+1; 64 lanes = 4 edge-slots x 16 ch;
// uniform ssrc loads + cndmask select by slot; interleaved 8-edge batches.
__global__ __launch_bounds__(BLK) void k_agg2(const unsigned short* __restrict__ h2,
                                              const int* __restrict__ rowbeg,
                                              const int* __restrict__ rowcnt,
                                              const int* __restrict__ ssrc,
                                              const float* __restrict__ dinv,
                                              const float* __restrict__ b2,
                                              float* __restrict__ out, int n) {
    int pair = __builtin_amdgcn_readfirstlane(
        (int)((blockIdx.x * BLK + threadIdx.x) >> 6));
    int lane = threadIdx.x & 63;
    int w0 = pair << 1;
    if (w0 >= n) return;
    int w1 = w0 + 1;
    bool has1 = (w1 < n);
    int q = lane >> 4;      // edge slot 0..3
    int c = lane & 15;      // channel
    int beg0 = rowbeg[w0], cnt0 = rowcnt[w0];
    int beg1 = 0, cnt1 = 0;
    if (has1) { beg1 = rowbeg[w1]; cnt1 = rowcnt[w1]; }
    float a0 = 0.f, a1 = 0.f;
    int e0 = 0, e1 = 0;
    while (e0 + 8 <= cnt0 && e1 + 8 <= cnt1) {
        int p0 = beg0 + e0, p1 = beg1 + e1;
        int x0 = ssrc[p0 + 0], x1 = ssrc[p0 + 1], x2 = ssrc[p0 + 2], x3 = ssrc[p0 + 3];
        int x4 = ssrc[p0 + 4], x5 = ssrc[p0 + 5], x6 = ssrc[p0 + 6], x7 = ssrc[p0 + 7];
        int y0 = ssrc[p1 + 0], y1 = ssrc[p1 + 1], y2 = ssrc[p1 + 2], y3 = ssrc[p1 + 3];
        int y4 = ssrc[p1 + 4], y5 = ssrc[p1 + 5], y6 = ssrc[p1 + 6], y7 = ssrc[p1 + 7];
        int sA0 = sel4(x0, x1, x2, x3, q), sB0 = sel4(x4, x5, x6, x7, q);
        int sA1 = sel4(y0, y1, y2, y3, q), sB1 = sel4(y4, y5, y6, y7, q);
        float vA0 = bf2f(h2[((size_t)sA0 << 4) + c]);
        float vB0 = bf2f(h2[((size_t)sB0 << 4) + c]);
        float vA1 = bf2f(h2[((size_t)sA1 << 4) + c]);
        float vB1 = bf2f(h2[((size_t)sB1 << 4) + c]);
        a0 += vA0 + vB0;
        a1 += vA1 + vB1;
        e0 += 8; e1 += 8;
    }
    // drain node 0
    for (; e0 + 8 <= cnt0; e0 += 8) {
        int p0 = beg0 + e0;
        int x0 = ssrc[p0 + 0], x1 = ssrc[p0 + 1], x2 = ssrc[p0 + 2], x3 = ssrc[p0 + 3];
        int x4 = ssrc[p0 + 4], x5 = ssrc[p0 + 5], x6 = ssrc[p0 + 6], x7 = ssrc[p0 + 7];
        int sA = sel4(x0, x1, x2, x3, q), sB = sel4(x4, x5, x6, x7, q);
        a0 += bf2f(h2[((size_t)sA << 4) + c]) + bf2f(h2[((size_t)sB << 4) + c]);
    }
    if (e0 + 4 <= cnt0) {
        int p0 = beg0 + e0;
        int x0 = ssrc[p0 + 0], x1 = ssrc[p0 + 1], x2 = ssrc[p0 + 2], x3 = ssrc[p0 + 3];
        a0 += bf2f(h2[((size_t)sel4(x0, x1, x2, x3, q) << 4) + c]);
        e0 += 4;
    }
    if (e0 + q < cnt0)
        a0 += bf2f(h2[((size_t)ssrc[beg0 + e0 + q] << 4) + c]);
    // drain node 1
    for (; e1 + 8 <= cnt1; e1 += 8) {
        int p1 = beg1 + e1;
        int y0 = ssrc[p1 + 0], y1 = ssrc[p1 + 1], y2 = ssrc[p1 + 2], y3 = ssrc[p1 + 3];
        int y4 = ssrc[p1 + 4], y5 = ssrc[p1 + 5], y6 = ssrc[p1 + 6], y7 = ssrc[p1 + 7];
        int sA = sel4(y0, y1, y2, y3, q), sB = sel4(y4, y5, y6, y7, q);
        a1 += bf2f(h2[((size_t)sA << 4) + c]) + bf2f(h2[((size_t)sB << 4) + c]);
    }
    if (has1 && e1 + 4 <= cnt1) {
        int p1 = beg1 + e1;
        int y0 = ssrc[p1 + 0], y1 = ssrc[p1 + 1], y2 = ssrc[p1 + 2], y3 = ssrc[p1 + 3];
        a1 += bf2f(h2[((size_t)sel4(y0, y1, y2, y3, q) << 4) + c]);
        e1 += 4;
    }
    if (has1 && e1 + q < cnt1)
        a1 += bf2f(h2[((size_t)ssrc[beg1 + e1 + q] << 4) + c]);

    a0 += __shfl_xor(a0, 16, 64);
    a0 += __shfl_xor(a0, 32, 64);
    a1 += __shfl_xor(a1, 16, 64);
    a1 += __shfl_xor(a1, 32, 64);
    if (q == 0) {
        float self0 = bf2f(h2[((size_t)w0 << 4) + c]);
        out[((size_t)w0 << 4) + c] = fmaf(dinv[w0], a0 + self0, b2[c]);
        if (has1) {
            float self1 = bf2f(h2[((size_t)w1 << 4) + c]);
            out[((size_t)w1 << 4) + c] = fmaf(dinv[w1], a1 + self1, b2[c]);
        }
    }
}

} // namespace

extern "C" void kernel_launch(void* const* d_in, const int* in_sizes, int n_in,
                              void* d_out, int out_size, void* d_ws, size_t ws_size,
                              hipStream_t stream) {
    const float* x  = (const float*)d_in[0];
    const int*   ei = (const int*)d_in[1];
    const float* W1 = (const float*)d_in[2];
    const float* b1 = (const float*)d_in[3];
    const float* W2 = (const float*)d_in[4];
    const float* b2 = (const float*)d_in[5];
    float* out = (float*)d_out;

    const int N = in_sizes[0] / 64;
    const int E = in_sizes[1] / 2;
    const int* src = ei;
    const int* dst = ei + E;
    const int nb = (N + NPB - 1) / NPB;   // buckets (<=1024)

    char* ws = (char*)d_ws;
    size_t off = 0;
    auto alloc = [&](size_t bytes) -> char* {
        char* p = ws + off;
        off = (off + bytes + 255) & ~(size_t)255;
        return p;
    };
    int*            bcnt   = (int*)alloc((size_t)1024 * CPAD * 4);
    int*            rowbeg = (int*)alloc((size_t)N * 4);
    int*            rowcnt = (int*)alloc((size_t)N * 4);
    float*          dinv   = (float*)alloc((size_t)N * 4);
    unsigned*       packed = (unsigned*)alloc((size_t)nb * STRIDE * 4);
    int*            ssrc   = (int*)alloc((size_t)nb * STRIDE * 4);
    unsigned short* hhat   = (unsigned short*)alloc((size_t)N * 64 * 2);
    unsigned short* h2hat  = (unsigned short*)alloc((size_t)N * 16 * 2);

    const int ntiles = (N + 255) / 256;
    const int g1grid = (ntiles < 1024) ? ntiles : 1024;
    const int nchunks = (E + PCHUNK - 1) / PCHUNK;
    const int npairs = (N + 1) / 2;
    const int nb_p = (int)(((long long)npairs * 64 + BLK - 1) / BLK);  // dual-node

    hipMemsetAsync(bcnt, 0, (size_t)nb * CPAD * 4, stream);
    k_part<<<nchunks, BLK, 0, stream>>>(src, dst, bcnt, packed, E, nb);
    k_sort<<<nb * 4, BLK, 0, stream>>>(packed, bcnt, ssrc, rowbeg, rowcnt, dinv, N);

    k_gemm1<<<g1grid, BLK, 0, stream>>>(x, W1, dinv, hhat, N, ntiles);
    k_agg1<<<nb_p, BLK, 0, stream>>>(hhat, rowbeg, rowcnt, ssrc, dinv, b1, W2,
                                     h2hat, N);
    k_agg2<<<nb_p, BLK, 0, stream>>>(h2hat, rowbeg, rowcnt, ssrc, dinv, b2, out, N);
}

// Round 4
// 201.059 us; speedup vs baseline: 1.3326x; 1.0658x over previous
//
#include <hip/hip_runtime.h>

// 2-layer GCN. memset(bcnt) -> part (bucket partition, PCHUNK=8192) ->
// meta (per-bucket histogram+scan -> rowbeg/rowcnt/dinv, 1x work) ->
// sortgemm (scatter-only counting sort, 2-way half-split per bucket, FUSED
// with the layer-1 GEMM as extra blocks; gemm reads meta's dinv and writes
// PRE-SCALED bf16 hhat) -> agg1 (dual-node waves, fused layer-2 GEMV,
// UNTOUCHED since r0) -> agg2 (dual-node waves).
// Lessons: agg1 is L2-miss-concurrency bound (~11MB unique/XCD ~= 44us) — do
// NOT touch its gather chain (per-edge dinv: +12us, r1). Do NOT use global
// per-node atomics (cross-XCD ping-pong: part +45us, r2). PCHUNK=8192 is the
// part optimum: smaller chunks write-amplify packed lines (2048: +14us, r3).
// This round: sort split into meta (1x histogram) + scatter-only, gemm fused
// into the scatter launch so it runs in sort's shadow.

namespace {
constexpr int BLK = 256;
constexpr int NPB = 256;       // nodes per bucket (dstLocal fits in 8 bits)
constexpr int PCHUNK = 8192;   // edges per partition block (r3: 2048 regresses)
constexpr int STRIDE = 5120;   // padded region per bucket: mean 4096 + 16 sigma
constexpr int CPAD = 32;       // bcnt padding: 1 counter per 128 B line

__device__ inline float bf2f(unsigned short h) {
    union { unsigned u; float f; } v; v.u = (unsigned)h << 16; return v.f;
}
__device__ inline unsigned short f2bf(float f) {
    union { float f; unsigned u; } v; v.f = f;
    unsigned r = (v.u + 0x7FFFu + ((v.u >> 16) & 1u)) >> 16;  // RNE
    return (unsigned short)r;
}
__device__ inline unsigned pack2bf(float a, float b) {
    return (unsigned)f2bf(a) | ((unsigned)f2bf(b) << 16);
}
// select one of 4 scalar edge ids by lane slot q (0..3) — cndmask tree
__device__ inline int sel4(int s0, int s1, int s2, int s3, int q) {
    int sa = (q & 1) ? s1 : s0;
    int sb = (q & 1) ? s3 : s2;
    return (q & 2) ? sb : sa;
}

// 8 / 4-edge gather helpers (indices wave-uniform -> scalar cache).
// hhat rows are PRE-SCALED by dinv[src]; keep this chain minimal (r1 lesson).
__device__ inline float gather8(const unsigned short* __restrict__ hhat,
                                const int* __restrict__ ssrc, int base, int lane) {
    int s0 = ssrc[base + 0], s1 = ssrc[base + 1];
    int s2 = ssrc[base + 2], s3 = ssrc[base + 3];
    int s4 = ssrc[base + 4], s5 = ssrc[base + 5];
    int s6 = ssrc[base + 6], s7 = ssrc[base + 7];
    float v0 = bf2f(hhat[((size_t)s0 << 6) + lane]);
    float v1 = bf2f(hhat[((size_t)s1 << 6) + lane]);
    float v2 = bf2f(hhat[((size_t)s2 << 6) + lane]);
    float v3 = bf2f(hhat[((size_t)s3 << 6) + lane]);
    float v4 = bf2f(hhat[((size_t)s4 << 6) + lane]);
    float v5 = bf2f(hhat[((size_t)s5 << 6) + lane]);
    float v6 = bf2f(hhat[((size_t)s6 << 6) + lane]);
    float v7 = bf2f(hhat[((size_t)s7 << 6) + lane]);
    return ((v0 + v1) + (v2 + v3)) + ((v4 + v5) + (v6 + v7));
}
__device__ inline float gather4(const unsigned short* __restrict__ hhat,
                                const int* __restrict__ ssrc, int base, int lane) {
    int s0 = ssrc[base + 0], s1 = ssrc[base + 1];
    int s2 = ssrc[base + 2], s3 = ssrc[base + 3];
    float v0 = bf2f(hhat[((size_t)s0 << 6) + lane]);
    float v1 = bf2f(hhat[((size_t)s1 << 6) + lane]);
    float v2 = bf2f(hhat[((size_t)s2 << 6) + lane]);
    float v3 = bf2f(hhat[((size_t)s3 << 6) + lane]);
    return (v0 + v1) + (v2 + v3);
}

// ---- stage 1: single-pass partition into fixed bucket regions --------------
__global__ __launch_bounds__(BLK) void k_part(const int* __restrict__ src,
                                              const int* __restrict__ dst,
                                              int* __restrict__ bcnt,
                                              unsigned* __restrict__ packed,
                                              int e, int nb) {
    __shared__ int hist[1024];
    __shared__ int base[1024];
    int t = threadIdx.x;
    int chunk0 = blockIdx.x * PCHUNK;
    if (chunk0 >= e) return;
    int lim = min(PCHUNK, e - chunk0);
    int lim4 = lim >> 2;
    for (int i = t; i < nb; i += BLK) hist[i] = 0;
    __syncthreads();
    const int4* d4 = (const int4*)(dst + chunk0);
    for (int i = t; i < lim4; i += BLK) {
        int4 d = d4[i];
        atomicAdd(&hist[d.x >> 8], 1);
        atomicAdd(&hist[d.y >> 8], 1);
        atomicAdd(&hist[d.z >> 8], 1);
        atomicAdd(&hist[d.w >> 8], 1);
    }
    for (int i = (lim4 << 2) + t; i < lim; i += BLK)
        atomicAdd(&hist[dst[chunk0 + i] >> 8], 1);
    __syncthreads();
    for (int i = t; i < nb; i += BLK) {
        int c = hist[i];
        base[i] = c ? (i * STRIDE + atomicAdd(&bcnt[i * CPAD], c)) : 0;
        hist[i] = 0;  // reuse as within-chunk cursor
    }
    __syncthreads();
    const int4* s4 = (const int4*)(src + chunk0);
    for (int i = t; i < lim4; i += BLK) {
        int4 d = d4[i];
        int4 s = s4[i];
        int b0 = d.x >> 8, b1 = d.y >> 8, b2 = d.z >> 8, b3 = d.w >> 8;
        int r0 = atomicAdd(&hist[b0], 1);
        packed[base[b0] + r0] = ((unsigned)s.x << 8) | (unsigned)(d.x & 255);
        int r1 = atomicAdd(&hist[b1], 1);
        packed[base[b1] + r1] = ((unsigned)s.y << 8) | (unsigned)(d.y & 255);
        int r2 = atomicAdd(&hist[b2], 1);
        packed[base[b2] + r2] = ((unsigned)s.z << 8) | (unsigned)(d.z & 255);
        int r3 = atomicAdd(&hist[b3], 1);
        packed[base[b3] + r3] = ((unsigned)s.w << 8) | (unsigned)(d.w & 255);
    }
    for (int i = (lim4 << 2) + t; i < lim; i += BLK) {
        int d = dst[chunk0 + i];
        int b = d >> 8;
        int r = atomicAdd(&hist[b], 1);
        packed[base[b] + r] = ((unsigned)src[chunk0 + i] << 8) | (unsigned)(d & 255);
    }
}

// ---- stage 2a: per-bucket histogram + scan -> row metadata (1x work) -------
__global__ __launch_bounds__(BLK) void k_meta(const unsigned* __restrict__ packed,
                                              const int* __restrict__ bcnt,
                                              int* __restrict__ rowbeg,
                                              int* __restrict__ rowcnt,
                                              float* __restrict__ dinv, int n) {
    __shared__ int cnt[NPB];
    __shared__ int offs[NPB];
    int b = blockIdx.x;
    int t = threadIdx.x;
    int regionBase = b * STRIDE;
    int ecnt = bcnt[b * CPAD];
    cnt[t] = 0;
    __syncthreads();
    int e4 = ecnt >> 2;
    const uint4* p4 = (const uint4*)(packed + regionBase);
    for (int i = t; i < e4; i += BLK) {
        uint4 p = p4[i];
        atomicAdd(&cnt[p.x & 255u], 1);
        atomicAdd(&cnt[p.y & 255u], 1);
        atomicAdd(&cnt[p.z & 255u], 1);
        atomicAdd(&cnt[p.w & 255u], 1);
    }
    for (int i = (e4 << 2) + t; i < ecnt; i += BLK)
        atomicAdd(&cnt[packed[regionBase + i] & 255u], 1);
    __syncthreads();
    int v = cnt[t];
    offs[t] = v;
    __syncthreads();
    for (int off = 1; off < NPB; off <<= 1) {
        int x = (t >= off) ? offs[t - off] : 0;
        __syncthreads();
        offs[t] += x;
        __syncthreads();
    }
    int node = (b << 8) + t;
    if (node < n) {
        rowbeg[node] = regionBase + offs[t] - v;  // exclusive prefix
        rowcnt[node] = v;
        dinv[node] = rsqrtf((float)(v + 1));      // +1 self-loop
    }
}

// ---- stage 2b: scatter-only sort FUSED with layer-1 GEMM -------------------
// Blocks [0, nsort): per-(bucket, half) scatter. Cursors seeded from rowbeg
// (meta), single pass over packed, no histogram/scan/staging (LDS = 1 KB).
// Blocks [nsort, ...): r0's grid-stride persistent GEMM (reads meta's dinv,
// writes PRE-SCALED bf16 hhat). LDS union = 16 KB -> all blocks co-resident.
union SMemU {
    int cnt[NPB];
    float W[64 * 64];
};

__global__ __launch_bounds__(BLK) void k_sortgemm(
    const unsigned* __restrict__ packed, const int* __restrict__ bcnt,
    const int* __restrict__ rowbeg, int* __restrict__ ssrc, int nsort, int n,
    const float* __restrict__ x, const float* __restrict__ W1,
    const float* __restrict__ dinv, unsigned short* __restrict__ hhat,
    int ntiles) {
    __shared__ SMemU sm;
    int t = threadIdx.x;
    if ((int)blockIdx.x < nsort) {
        // ---------------- scatter role ----------------
        int bid = blockIdx.x;
        int b = bid >> 1;
        int hf = bid & 1;              // half: local nodes hf*128 .. hf*128+127
        int regionBase = b * STRIDE;
        int ecnt = bcnt[b * CPAD];
        int node = (b << 8) + t;
        sm.cnt[t] = (node < n) ? rowbeg[node] : 0;   // absolute cursor
        __syncthreads();
        int lo = hf << 7, hi = lo + 128;
        int e4 = ecnt >> 2;
        const uint4* p4 = (const uint4*)(packed + regionBase);
        for (int i = t; i < e4; i += BLK) {
            uint4 pp = p4[i];
            unsigned a[4] = {pp.x, pp.y, pp.z, pp.w};
            #pragma unroll
            for (int k = 0; k < 4; ++k) {
                int dl = (int)(a[k] & 255u);
                if (dl >= lo && dl < hi) {
                    int pos = atomicAdd(&sm.cnt[dl], 1);
                    ssrc[pos] = (int)(a[k] >> 8);
                }
            }
        }
        for (int i = (e4 << 2) + t; i < ecnt; i += BLK) {
            unsigned p = packed[regionBase + i];
            int dl = (int)(p & 255u);
            if (dl >= lo && dl < hi) {
                int pos = atomicAdd(&sm.cnt[dl], 1);
                ssrc[pos] = (int)(p >> 8);
            }
        }
    } else {
        // ---------------- gemm role ----------------
        // hhat[n][c] = bf16( dinv[n] * sum_k x[n][k]*W1[k][c] )
        #pragma unroll
        for (int i = 0; i < 16; ++i) sm.W[t + BLK * i] = W1[t + BLK * i];
        __syncthreads();
        const int cg = t & 3;
        const int ng = t >> 2;
        const float* Wc = sm.W + cg * 16;
        const int g1grid = gridDim.x - nsort;

        for (int tile = blockIdx.x - nsort; tile < ntiles; tile += g1grid) {
            const int node0 = tile * 256 + ng * 4;
            int nd[4];
            #pragma unroll
            for (int i = 0; i < 4; ++i) {
                int vv = node0 + i;
                nd[i] = (vv < n) ? vv : (n - 1);
            }
            float4 acc[4][4];
            #pragma unroll
            for (int i = 0; i < 4; ++i)
                #pragma unroll
                for (int c = 0; c < 4; ++c) acc[i][c] = make_float4(0.f, 0.f, 0.f, 0.f);

            for (int k4 = 0; k4 < 16; ++k4) {
                float4 xv[4];
                #pragma unroll
                for (int i = 0; i < 4; ++i)
                    xv[i] = ((const float4*)(x + (size_t)nd[i] * 64))[k4];
                #pragma unroll
                for (int kk = 0; kk < 4; ++kk) {
                    const float4* wr = (const float4*)(Wc + (k4 * 4 + kk) * 64);
                    float4 w0 = wr[0], w1 = wr[1], w2 = wr[2], w3 = wr[3];
                    #pragma unroll
                    for (int i = 0; i < 4; ++i) {
                        float xa[4] = {xv[i].x, xv[i].y, xv[i].z, xv[i].w};
                        float xs = xa[kk];
                        acc[i][0].x = fmaf(xs, w0.x, acc[i][0].x);
                        acc[i][0].y = fmaf(xs, w0.y, acc[i][0].y);
                        acc[i][0].z = fmaf(xs, w0.z, acc[i][0].z);
                        acc[i][0].w = fmaf(xs, w0.w, acc[i][0].w);
                        acc[i][1].x = fmaf(xs, w1.x, acc[i][1].x);
                        acc[i][1].y = fmaf(xs, w1.y, acc[i][1].y);
                        acc[i][1].z = fmaf(xs, w1.z, acc[i][1].z);
                        acc[i][1].w = fmaf(xs, w1.w, acc[i][1].w);
                        acc[i][2].x = fmaf(xs, w2.x, acc[i][2].x);
                        acc[i][2].y = fmaf(xs, w2.y, acc[i][2].y);
                        acc[i][2].z = fmaf(xs, w2.z, acc[i][2].z);
                        acc[i][2].w = fmaf(xs, w2.w, acc[i][2].w);
                        acc[i][3].x = fmaf(xs, w3.x, acc[i][3].x);
                        acc[i][3].y = fmaf(xs, w3.y, acc[i][3].y);
                        acc[i][3].z = fmaf(xs, w3.z, acc[i][3].z);
                        acc[i][3].w = fmaf(xs, w3.w, acc[i][3].w);
                    }
                }
            }
            #pragma unroll
            for (int i = 0; i < 4; ++i) {
                int vv = node0 + i;
                if (vv < n) {
                    float d = dinv[vv];
                    unsigned u0 = pack2bf(acc[i][0].x * d, acc[i][0].y * d);
                    unsigned u1 = pack2bf(acc[i][0].z * d, acc[i][0].w * d);
                    unsigned u2 = pack2bf(acc[i][1].x * d, acc[i][1].y * d);
                    unsigned u3 = pack2bf(acc[i][1].z * d, acc[i][1].w * d);
                    unsigned u4 = pack2bf(acc[i][2].x * d, acc[i][2].y * d);
                    unsigned u5 = pack2bf(acc[i][2].z * d, acc[i][2].w * d);
                    unsigned u6 = pack2bf(acc[i][3].x * d, acc[i][3].y * d);
                    unsigned u7 = pack2bf(acc[i][3].z * d, acc[i][3].w * d);
                    uint4* dstp = (uint4*)(hhat + (size_t)vv * 64 + cg * 16);
                    dstp[0] = make_uint4(u0, u1, u2, u3);
                    dstp[1] = make_uint4(u4, u5, u6, u7);
                }
            }
        }
    }
}

// ---- layer kernels ---------------------------------------------------------

// DUAL-node wave: nodes 2w and 2w+1, lane = channel (64). Interleaved 8-edge
// batches (up to 16 gathers in flight). All metadata/index loads wave-uniform.
// Fused layer-2 GEMV epilogue per node. (r0 verified champion — DO NOT TOUCH)
__global__ __launch_bounds__(BLK) void k_agg1(const unsigned short* __restrict__ hhat,
                                              const int* __restrict__ rowbeg,
                                              const int* __restrict__ rowcnt,
                                              const int* __restrict__ ssrc,
                                              const float* __restrict__ dinv,
                                              const float* __restrict__ b1,
                                              const float* __restrict__ W2,
                                              unsigned short* __restrict__ h2hat, int n) {
    int pair = __builtin_amdgcn_readfirstlane(
        (int)((blockIdx.x * BLK + threadIdx.x) >> 6));
    int lane = threadIdx.x & 63;
    int wid0 = pair << 1;
    if (wid0 >= n) return;
    int wid1 = wid0 + 1;
    bool has1 = (wid1 < n);
    const int g = lane >> 4;   // c-group for the fused GEMV
    const int j = lane & 15;   // output channel for the fused GEMV
    float w2r[16];
    #pragma unroll
    for (int k = 0; k < 16; ++k) w2r[k] = W2[(g * 16 + k) * 16 + j];

    int beg0 = rowbeg[wid0], cnt0 = rowcnt[wid0];
    int beg1 = 0, cnt1 = 0;
    if (has1) { beg1 = rowbeg[wid1]; cnt1 = rowcnt[wid1]; }
    float a0 = bf2f(hhat[((size_t)wid0 << 6) + lane]);  // self-loop
    float a1 = 0.f;
    if (has1) a1 = bf2f(hhat[((size_t)wid1 << 6) + lane]);
    int e0 = 0, e1 = 0;
    // interleaved main: 16 gathers in flight
    while (e0 + 8 <= cnt0 && e1 + 8 <= cnt1) {
        float r0 = gather8(hhat, ssrc, beg0 + e0, lane);
        float r1 = gather8(hhat, ssrc, beg1 + e1, lane);
        a0 += r0;
        a1 += r1;
        e0 += 8; e1 += 8;
    }
    for (; e0 + 8 <= cnt0; e0 += 8) a0 += gather8(hhat, ssrc, beg0 + e0, lane);
    for (; e1 + 8 <= cnt1; e1 += 8) a1 += gather8(hhat, ssrc, beg1 + e1, lane);
    if (e0 + 4 <= cnt0) { a0 += gather4(hhat, ssrc, beg0 + e0, lane); e0 += 4; }
    if (e1 + 4 <= cnt1) { a1 += gather4(hhat, ssrc, beg1 + e1, lane); e1 += 4; }
    for (; e0 < cnt0; ++e0) a0 += bf2f(hhat[((size_t)ssrc[beg0 + e0] << 6) + lane]);
    for (; e1 < cnt1; ++e1) a1 += bf2f(hhat[((size_t)ssrc[beg1 + e1] << 6) + lane]);

    // fused GEMV epilogue, node 0
    {
        float dv = dinv[wid0];
        float h = fmaxf(fmaf(dv, a0, b1[lane]), 0.f);
        float part = 0.f;
        #pragma unroll
        for (int k = 0; k < 16; ++k)
            part = fmaf(__shfl(h, g * 16 + k, 64), w2r[k], part);
        part += __shfl_xor(part, 16, 64);
        part += __shfl_xor(part, 32, 64);
        if (g == 0) h2hat[(size_t)wid0 * 16 + j] = f2bf(part * dv);
    }
    if (has1) {
        float dv = dinv[wid1];
        float h = fmaxf(fmaf(dv, a1, b1[lane]), 0.f);
        float part = 0.f;
        #pragma unroll
        for (int k = 0; k < 16; ++k)
            part = fmaf(__shfl(h, g * 16 + k, 64), w2r[k], part);
        part += __shfl_xor(part, 16, 64);
        part += __shfl_xor(part, 32, 64);
        if (g == 0) h2hat[(size_t)wid1 * 16 + j] = f2bf(part * dv);
    }
}

// DUAL-node wave layer 2: nodes 2w, 2w+1; 64 lanes = 4 edge-slots x 16 ch;
// uniform ssrc loads + cndmask select by slot; interleaved 8-edge batches.
__global__ __launch_bounds__(BLK) void k_agg2(const unsigned short* __restrict__ h2,
                                              const int* __restrict__ rowbeg,
                                              const int* __restrict__ rowcnt,
                                              const int* __restrict__ ssrc,
                                              const float* __restrict__ dinv,
                                              const float* __restrict__ b2,
                                              float* __restrict__ out, int n) {
    int pair = __builtin_amdgcn_readfirstlane(
        (int)((blockIdx.x * BLK + threadIdx.x) >> 6));
    int lane = threadIdx.x & 63;
    int w0 = pair << 1;
    if (w0 >= n) return;
    int w1 = w0 + 1;
    bool has1 = (w1 < n);
    int q = lane >> 4;      // edge slot 0..3
    int c = lane & 15;      // channel
    int beg0 = rowbeg[w0], cnt0 = rowcnt[w0];
    int beg1 = 0, cnt1 = 0;
    if (has1) { beg1 = rowbeg[w1]; cnt1 = rowcnt[w1]; }
    float a0 = 0.f, a1 = 0.f;
    int e0 = 0, e1 = 0;
    while (e0 + 8 <= cnt0 && e1 + 8 <= cnt1) {
        int p0 = beg0 + e0, p1 = beg1 + e1;
        int x0 = ssrc[p0 + 0], x1 = ssrc[p0 + 1], x2 = ssrc[p0 + 2], x3 = ssrc[p0 + 3];
        int x4 = ssrc[p0 + 4], x5 = ssrc[p0 + 5], x6 = ssrc[p0 + 6], x7 = ssrc[p0 + 7];
        int y0 = ssrc[p1 + 0], y1 = ssrc[p1 + 1], y2 = ssrc[p1 + 2], y3 = ssrc[p1 + 3];
        int y4 = ssrc[p1 + 4], y5 = ssrc[p1 + 5], y6 = ssrc[p1 + 6], y7 = ssrc[p1 + 7];
        int sA0 = sel4(x0, x1, x2, x3, q), sB0 = sel4(x4, x5, x6, x7, q);
        int sA1 = sel4(y0, y1, y2, y3, q), sB1 = sel4(y4, y5, y6, y7, q);
        float vA0 = bf2f(h2[((size_t)sA0 << 4) + c]);
        float vB0 = bf2f(h2[((size_t)sB0 << 4) + c]);
        float vA1 = bf2f(h2[((size_t)sA1 << 4) + c]);
        float vB1 = bf2f(h2[((size_t)sB1 << 4) + c]);
        a0 += vA0 + vB0;
        a1 += vA1 + vB1;
        e0 += 8; e1 += 8;
    }
    // drain node 0
    for (; e0 + 8 <= cnt0; e0 += 8) {
        int p0 = beg0 + e0;
        int x0 = ssrc[p0 + 0], x1 = ssrc[p0 + 1], x2 = ssrc[p0 + 2], x3 = ssrc[p0 + 3];
        int x4 = ssrc[p0 + 4], x5 = ssrc[p0 + 5], x6 = ssrc[p0 + 6], x7 = ssrc[p0 + 7];
        int sA = sel4(x0, x1, x2, x3, q), sB = sel4(x4, x5, x6, x7, q);
        a0 += bf2f(h2[((size_t)sA << 4) + c]) + bf2f(h2[((size_t)sB << 4) + c]);
    }
    if (e0 + 4 <= cnt0) {
        int p0 = beg0 + e0;
        int x0 = ssrc[p0 + 0], x1 = ssrc[p0 + 1], x2 = ssrc[p0 + 2], x3 = ssrc[p0 + 3];
        a0 += bf2f(h2[((size_t)sel4(x0, x1, x2, x3, q) << 4) + c]);
        e0 += 4;
    }
    if (e0 + q < cnt0)
        a0 += bf2f(h2[((size_t)ssrc[beg0 + e0 + q] << 4) + c]);
    // drain node 1
    for (; e1 + 8 <= cnt1; e1 += 8) {
        int p1 = beg1 + e1;
        int y0 = ssrc[p1 + 0], y1 = ssrc[p1 + 1], y2 = ssrc[p1 + 2], y3 = ssrc[p1 + 3];
        int y4 = ssrc[p1 + 4], y5 = ssrc[p1 + 5], y6 = ssrc[p1 + 6], y7 = ssrc[p1 + 7];
        int sA = sel4(y0, y1, y2, y3, q), sB = sel4(y4, y5, y6, y7, q);
        a1 += bf2f(h2[((size_t)sA << 4) + c]) + bf2f(h2[((size_t)sB << 4) + c]);
    }
    if (has1 && e1 + 4 <= cnt1) {
        int p1 = beg1 + e1;
        int y0 = ssrc[p1 + 0], y1 = ssrc[p1 + 1], y2 = ssrc[p1 + 2], y3 = ssrc[p1 + 3];
        a1 += bf2f(h2[((size_t)sel4(y0, y1, y2, y3, q) << 4) + c]);
        e1 += 4;
    }
    if (has1 && e1 + q < cnt1)
        a1 += bf2f(h2[((size_t)ssrc[beg1 + e1 + q] << 4) + c]);

    a0 += __shfl_xor(a0, 16, 64);
    a0 += __shfl_xor(a0, 32, 64);
    a1 += __shfl_xor(a1, 16, 64);
    a1 += __shfl_xor(a1, 32, 64);
    if (q == 0) {
        float self0 = bf2f(h2[((size_t)w0 << 4) + c]);
        out[((size_t)w0 << 4) + c] = fmaf(dinv[w0], a0 + self0, b2[c]);
        if (has1) {
            float self1 = bf2f(h2[((size_t)w1 << 4) + c]);
            out[((size_t)w1 << 4) + c] = fmaf(dinv[w1], a1 + self1, b2[c]);
        }
    }
}

} // namespace

extern "C" void kernel_launch(void* const* d_in, const int* in_sizes, int n_in,
                              void* d_out, int out_size, void* d_ws, size_t ws_size,
                              hipStream_t stream) {
    const float* x  = (const float*)d_in[0];
    const int*   ei = (const int*)d_in[1];
    const float* W1 = (const float*)d_in[2];
    const float* b1 = (const float*)d_in[3];
    const float* W2 = (const float*)d_in[4];
    const float* b2 = (const float*)d_in[5];
    float* out = (float*)d_out;

    const int N = in_sizes[0] / 64;
    const int E = in_sizes[1] / 2;
    const int* src = ei;
    const int* dst = ei + E;
    const int nb = (N + NPB - 1) / NPB;   // buckets (<=1024)

    char* ws = (char*)d_ws;
    size_t off = 0;
    auto alloc = [&](size_t bytes) -> char* {
        char* p = ws + off;
        off = (off + bytes + 255) & ~(size_t)255;
        return p;
    };
    int*            bcnt   = (int*)alloc((size_t)1024 * CPAD * 4);
    int*            rowbeg = (int*)alloc((size_t)N * 4);
    int*            rowcnt = (int*)alloc((size_t)N * 4);
    float*          dinv   = (float*)alloc((size_t)N * 4);
    unsigned*       packed = (unsigned*)alloc((size_t)nb * STRIDE * 4);
    int*            ssrc   = (int*)alloc((size_t)nb * STRIDE * 4);
    unsigned short* hhat   = (unsigned short*)alloc((size_t)N * 64 * 2);
    unsigned short* h2hat  = (unsigned short*)alloc((size_t)N * 16 * 2);

    const int ntiles = (N + 255) / 256;
    const int g1grid = (ntiles < 1024) ? ntiles : 1024;
    const int nchunks = (E + PCHUNK - 1) / PCHUNK;
    const int npairs = (N + 1) / 2;
    const int nb_p = (int)(((long long)npairs * 64 + BLK - 1) / BLK);  // dual-node
    const int nsort = nb * 2;   // 2-way half-split scatter blocks

    hipMemsetAsync(bcnt, 0, (size_t)nb * CPAD * 4, stream);
    k_part<<<nchunks, BLK, 0, stream>>>(src, dst, bcnt, packed, E, nb);
    k_meta<<<nb, BLK, 0, stream>>>(packed, bcnt, rowbeg, rowcnt, dinv, N);
    k_sortgemm<<<nsort + g1grid, BLK, 0, stream>>>(packed, bcnt, rowbeg, ssrc,
                                                   nsort, N, x, W1, dinv, hhat,
                                                   ntiles);
    k_agg1<<<nb_p, BLK, 0, stream>>>(hhat, rowbeg, rowcnt, ssrc, dinv, b1, W2,
                                     h2hat, N);
    k_agg2<<<nb_p, BLK, 0, stream>>>(h2hat, rowbeg, rowcnt, ssrc, dinv, b2, out, N);
}